// Round 6
// baseline (93.886 us; speedup 1.0000x reference)
//
#include <hip/hip_runtime.h>
#include <hip/hip_bf16.h>

// Problem constants
#define NA 32      // agents per graph
#define NACT 64    // actions
#define NIN 128    // in_dim
#define NOUT 128   // out_dim
#define NB 256     // graphs
// Inputs f32. Outputs f32: obs_final [8192,32,192] then w_out [8192,32,1].

// ---------------------------------------------------------------------------
// Kernel A (unchanged from round 5): per-graph QK projection + softmax.
// grid = 256, block = 1024.
// ---------------------------------------------------------------------------
__global__ __launch_bounds__(1024) void qk_softmax_kernel(
    const float* __restrict__ h,
    const float* __restrict__ Wk, const float* __restrict__ bk,
    const float* __restrict__ Wq, const float* __restrict__ bq,
    float* __restrict__ w_out)
{
    __shared__ float sh[NA][NIN];
    __shared__ float sK[NA][NOUT + 4];
    __shared__ float sQ[NA][NOUT + 4];

    const int b   = blockIdx.x;
    const int tid = threadIdx.x;

    {
        const float4* src = reinterpret_cast<const float4*>(h + (size_t)b * NA * NIN);
        reinterpret_cast<float4*>(&sh[0][0])[tid] = src[tid];
    }
    __syncthreads();

    const int tx = tid & 127;
    const int ty = tid >> 7;
    float ak[4], aq[4];
    {
        const float bkv = bk[tx];
        const float bqv = bq[tx];
#pragma unroll
        for (int s = 0; s < 4; ++s) { ak[s] = bkv; aq[s] = bqv; }
    }
    for (int r = 0; r < NIN; r += 4) {
        const float wk0 = Wk[(r + 0) * NOUT + tx];
        const float wk1 = Wk[(r + 1) * NOUT + tx];
        const float wk2 = Wk[(r + 2) * NOUT + tx];
        const float wk3 = Wk[(r + 3) * NOUT + tx];
        const float wq0 = Wq[(r + 0) * NOUT + tx];
        const float wq1 = Wq[(r + 1) * NOUT + tx];
        const float wq2 = Wq[(r + 2) * NOUT + tx];
        const float wq3 = Wq[(r + 3) * NOUT + tx];
#pragma unroll
        for (int s = 0; s < 4; ++s) {
            const int n = ty * 4 + s;
            const float4 hv = *reinterpret_cast<const float4*>(&sh[n][r]);
            ak[s] = fmaf(hv.x, wk0, fmaf(hv.y, wk1, fmaf(hv.z, wk2, fmaf(hv.w, wk3, ak[s]))));
            aq[s] = fmaf(hv.x, wq0, fmaf(hv.y, wq1, fmaf(hv.z, wq2, fmaf(hv.w, wq3, aq[s]))));
        }
    }
#pragma unroll
    for (int s = 0; s < 4; ++s) {
        const int n = ty * 4 + s;
        sK[n][tx] = ak[s];
        sQ[n][tx] = aq[s];
    }
    __syncthreads();

    const int i = tid >> 5;
    const int j = tid & 31;
    float sc = 0.f;
    for (int r = 0; r < NOUT; r += 4) {
        const float4 qv = *reinterpret_cast<const float4*>(&sQ[i][r]);
        const float4 kv = *reinterpret_cast<const float4*>(&sK[j][r]);
        sc = fmaf(qv.x, kv.x, fmaf(qv.y, kv.y, fmaf(qv.z, kv.z, fmaf(qv.w, kv.w, sc))));
    }
    sc *= 0.08838834764831845f;  // 1/sqrt(128)

    float m = sc;
#pragma unroll
    for (int off = 16; off >= 1; off >>= 1) m = fmaxf(m, __shfl_xor(m, off));
    const float e = __expf(sc - m);
    float ssum = e;
#pragma unroll
    for (int off = 16; off >= 1; off >>= 1) ssum += __shfl_xor(ssum, off);
    const float w = e / ssum;

    w_out[(size_t)b * (NA * NA) + tid] = w;   // (b*32+i)*32 + j
}

// ---------------------------------------------------------------------------
// Kernel B (rewritten): register-resident z_mix.
// Thread (t = tid>>3, q = tid&7) owns row t, cols q*8..q*8+7.
// Loads are contiguous (addr = 8*tid floats). Row-sum over the 32 t's via
// in-wave shfl_xor(8,16,32) butterfly + 1KB LDS combine across 4 waves.
// LDS ~1.3 KB -> 8 blocks/CU (32 waves), 2 syncthreads.
// grid = 8192, block = 256.
// ---------------------------------------------------------------------------
__global__ __launch_bounds__(256) void mix_kernel(
    const float* __restrict__ policies, const float* __restrict__ actions,
    const float* __restrict__ obs, const float* __restrict__ noise,
    const float* __restrict__ w_in, float* __restrict__ out)
{
    __shared__ float spart[4][NACT];  // per-wave partial column sums
    __shared__ float szm[NACT];       // zmean

    const int blk = blockIdx.x;       // = b*32 + i
    const int b   = blk >> 5;
    const int tid = threadIdx.x;
    const int t   = tid >> 3;         // src row 0..31
    const int q   = tid & 7;          // col group
    const int c0  = q * 8;

    // ---- load pi/act/noise rows into registers (contiguous: 8*tid floats)
    const float4* pi4 = reinterpret_cast<const float4*>(policies + (size_t)b * 2048) + 2 * tid;
    const float4* ac4 = reinterpret_cast<const float4*>(actions  + (size_t)b * 2048) + 2 * tid;
    const float4* nz4 = reinterpret_cast<const float4*>(noise    + (size_t)blk * 2048) + 2 * tid;
    const float4 pA = pi4[0], pB = pi4[1];
    const float4 aA = ac4[0], aB = ac4[1];
    const float4 nA = nz4[0], nB = nz4[1];
    const float  wt = w_in[(size_t)blk * NA + t];

    float pi[8] = {pA.x, pA.y, pA.z, pA.w, pB.x, pB.y, pB.z, pB.w};
    float ac[8] = {aA.x, aA.y, aA.z, aA.w, aB.x, aB.y, aB.z, aB.w};
    float nz[8] = {nA.x, nA.y, nA.z, nA.w, nB.x, nB.y, nB.z, nB.w};

    // z = w_t*(act-pi) + pi + noise
    float z[8];
#pragma unroll
    for (int k = 0; k < 8; ++k) z[k] = fmaf(wt, ac[k] - pi[k], pi[k]) + nz[k];

    // ---- butterfly sum over the 8 t's in this wave (lanes xor 8,16,32)
    const int wv  = tid >> 6;   // wave 0..3 (covers t = wv*8 .. wv*8+7)
    const int lil = tid & 63;
#pragma unroll
    for (int k = 0; k < 8; ++k) {
        float s = z[k];
        s += __shfl_xor(s, 8);
        s += __shfl_xor(s, 16);
        s += __shfl_xor(s, 32);
        if (lil < 8) spart[wv][lil * 8 + k] = s;   // lane lil holds cols lil*8+k
    }

    // ---- obs copy (independent of reduction; overlaps the barrier wait)
    const float4* obs4 = reinterpret_cast<const float4*>(obs + (size_t)b * NA * NIN);
    float4* out4 = reinterpret_cast<float4*>(out) + (size_t)blk * 1536;
#pragma unroll
    for (int k = 0; k < 4; ++k) {
        const int m  = tid + 256 * k;   // 0..1023
        const int tt = m >> 5;
        const int n  = m & 31;
        out4[tt * 48 + n] = obs4[tt * 32 + n];
    }

    __syncthreads();
    if (tid < NACT) {
        szm[tid] = (spart[0][tid] + spart[1][tid] + spart[2][tid] + spart[3][tid]) * (1.0f / NA);
    }
    __syncthreads();

    // ---- z_mix[t][c] = zmean[c] + (pi - z) / A ; write 8 floats (2 float4)
    const float4 zmA = *reinterpret_cast<const float4*>(&szm[c0]);
    const float4 zmB = *reinterpret_cast<const float4*>(&szm[c0 + 4]);
    const float zm[8] = {zmA.x, zmA.y, zmA.z, zmA.w, zmB.x, zmB.y, zmB.z, zmB.w};
    float o[8];
#pragma unroll
    for (int k = 0; k < 8; ++k) o[k] = fmaf(pi[k] - z[k], (1.0f / NA), zm[k]);

    float4* outz = out4 + t * 48 + 32 + q * 2;
    outz[0] = make_float4(o[0], o[1], o[2], o[3]);
    outz[1] = make_float4(o[4], o[5], o[6], o[7]);
}

extern "C" void kernel_launch(void* const* d_in, const int* in_sizes, int n_in,
                              void* d_out, int out_size, void* d_ws, size_t ws_size,
                              hipStream_t stream) {
    const float* h        = (const float*)d_in[0];
    const float* policies = (const float*)d_in[1];
    const float* actions  = (const float*)d_in[2];
    const float* obs_proc = (const float*)d_in[3];
    const float* noise    = (const float*)d_in[4];
    const float* Wk       = (const float*)d_in[5];
    const float* bk       = (const float*)d_in[6];
    const float* Wq       = (const float*)d_in[7];
    const float* bq       = (const float*)d_in[8];

    float* out = (float*)d_out;
    float* obs_final = out;                                      // [8192,32,192]
    float* w_out = out + (size_t)NB * NA * NA * (NIN + NACT);    // [8192,32,1]

    qk_softmax_kernel<<<NB, 1024, 0, stream>>>(h, Wk, bk, Wq, bq, w_out);
    mix_kernel<<<NB * NA, 256, 0, stream>>>(policies, actions, obs_proc, noise,
                                            w_out, obs_final);
}

// Round 7
// 73.783 us; speedup vs baseline: 1.2725x; 1.2725x over previous
//
#include <hip/hip_runtime.h>
#include <hip/hip_bf16.h>

// Problem constants
#define NA 32      // agents per graph
#define NACT 64    // actions
#define NIN 128    // in_dim
#define NOUT 128   // out_dim
#define NB 256     // graphs
// Inputs f32. Outputs f32: obs_final [8192,32,192] then w_out [8192,32,1].

// ---------------------------------------------------------------------------
// Fused kernel: one block per graph (grid=256, block=1024, 16 waves).
// Phase 1 (qk): stage h+obs, project K/Q, scores+softmax -> w in LDS + w_out.
// Phase 2 (mix): 4 groups x 256 threads; group g handles i = 4L+g, L=0..7.
//   pi/act in registers for the whole loop; noise prefetched one i ahead;
//   row-sum via in-wave shfl_xor(8,16,32) butterfly + spart/szm LDS combine.
// ---------------------------------------------------------------------------
__global__ __launch_bounds__(1024) void fused_kernel(
    const float* __restrict__ h,
    const float* __restrict__ Wk, const float* __restrict__ bk,
    const float* __restrict__ Wq, const float* __restrict__ bq,
    const float* __restrict__ policies, const float* __restrict__ actions,
    const float* __restrict__ obs, const float* __restrict__ noise,
    float* __restrict__ out, float* __restrict__ w_out)
{
    __shared__ float sh[NA][NIN];         // 16 KB
    __shared__ float sK[NA][NOUT + 4];    // 16.5 KB
    __shared__ float sQ[NA][NOUT + 4];    // 16.5 KB
    __shared__ float sw[NA][NA];          // 4 KB   w[i][j]
    __shared__ float sobs[NA * NIN];      // 16 KB
    __shared__ float spart[16][NACT];     // 4 KB   per-wave column partials
    __shared__ float szm[4][NACT];        // 1 KB   per-group zmean

    const int b   = blockIdx.x;
    const int tid = threadIdx.x;

    // ---- stage h + obs (1024 x float4 each)
    {
        const float4* hs = reinterpret_cast<const float4*>(h + (size_t)b * NA * NIN);
        reinterpret_cast<float4*>(&sh[0][0])[tid] = hs[tid];
        const float4* os = reinterpret_cast<const float4*>(obs + (size_t)b * NA * NIN);
        reinterpret_cast<float4*>(sobs)[tid] = os[tid];
    }

    // ---- prefetch pi/act (+ first noise) into registers (waits land at first use)
    const int g    = tid >> 8;     // mix group 0..3
    const int r256 = tid & 255;
    const int t    = r256 >> 3;    // src/dst row 0..31
    const int q    = r256 & 7;     // col group (8 floats)

    const float4* pi4 = reinterpret_cast<const float4*>(policies + (size_t)b * 2048) + 2 * r256;
    const float4* ac4 = reinterpret_cast<const float4*>(actions  + (size_t)b * 2048) + 2 * r256;
    const float4 pA = pi4[0], pB = pi4[1];
    const float4 aA = ac4[0], aB = ac4[1];
    const float4* nzf4 = reinterpret_cast<const float4*>(noise);
    const size_t nz0 = ((size_t)(b * NA) + g) * 512 + 2 * r256;
    float4 ncA = nzf4[nz0], ncB = nzf4[nz0 + 1];

    __syncthreads();

    // ---- phase 1: projection (thread: tx = out-dim, ty = node-group of 4)
    {
        const int tx = tid & 127;
        const int ty = tid >> 7;
        float ak[4], aq[4];
        const float bkv = bk[tx];
        const float bqv = bq[tx];
#pragma unroll
        for (int s = 0; s < 4; ++s) { ak[s] = bkv; aq[s] = bqv; }
        for (int r = 0; r < NIN; r += 4) {
            const float wk0 = Wk[(r + 0) * NOUT + tx];
            const float wk1 = Wk[(r + 1) * NOUT + tx];
            const float wk2 = Wk[(r + 2) * NOUT + tx];
            const float wk3 = Wk[(r + 3) * NOUT + tx];
            const float wq0 = Wq[(r + 0) * NOUT + tx];
            const float wq1 = Wq[(r + 1) * NOUT + tx];
            const float wq2 = Wq[(r + 2) * NOUT + tx];
            const float wq3 = Wq[(r + 3) * NOUT + tx];
#pragma unroll
            for (int s = 0; s < 4; ++s) {
                const int n = ty * 4 + s;
                const float4 hv = *reinterpret_cast<const float4*>(&sh[n][r]);
                ak[s] = fmaf(hv.x, wk0, fmaf(hv.y, wk1, fmaf(hv.z, wk2, fmaf(hv.w, wk3, ak[s]))));
                aq[s] = fmaf(hv.x, wq0, fmaf(hv.y, wq1, fmaf(hv.z, wq2, fmaf(hv.w, wq3, aq[s]))));
            }
        }
#pragma unroll
        for (int s = 0; s < 4; ++s) {
            const int n = ty * 4 + s;
            sK[n][tx] = ak[s];
            sQ[n][tx] = aq[s];
        }
    }
    __syncthreads();

    // ---- scores + softmax (thread: i = tid>>5 dst, j = tid&31 src)
    {
        const int i = tid >> 5;
        const int j = tid & 31;
        float sc = 0.f;
        for (int r = 0; r < NOUT; r += 4) {
            const float4 qv = *reinterpret_cast<const float4*>(&sQ[i][r]);
            const float4 kv = *reinterpret_cast<const float4*>(&sK[j][r]);
            sc = fmaf(qv.x, kv.x, fmaf(qv.y, kv.y, fmaf(qv.z, kv.z, fmaf(qv.w, kv.w, sc))));
        }
        sc *= 0.08838834764831845f;  // 1/sqrt(128)

        float m = sc;
#pragma unroll
        for (int off = 16; off >= 1; off >>= 1) m = fmaxf(m, __shfl_xor(m, off));
        const float e = __expf(sc - m);
        float ssum = e;
#pragma unroll
        for (int off = 16; off >= 1; off >>= 1) ssum += __shfl_xor(ssum, off);
        const float w = e / ssum;

        sw[i][j] = w;
        w_out[(size_t)b * (NA * NA) + tid] = w;
    }
    __syncthreads();

    // ---- phase 2: mix. Registers for pi and (act - pi); loop 8 i's per group.
    float pi_[8] = {pA.x, pA.y, pA.z, pA.w, pB.x, pB.y, pB.z, pB.w};
    float d_[8]  = {aA.x - pA.x, aA.y - pA.y, aA.z - pA.z, aA.w - pA.w,
                    aB.x - pB.x, aB.y - pB.y, aB.z - pB.z, aB.w - pB.w};
    float nzc[8] = {ncA.x, ncA.y, ncA.z, ncA.w, ncB.x, ncB.y, ncB.z, ncB.w};

    const int wv  = tid >> 6;   // block-wave 0..15
    const int lil = tid & 63;
    const float4* so4 = reinterpret_cast<const float4*>(sobs);

    for (int L = 0; L < 8; ++L) {
        const int i2 = L * 4 + g;

        // prefetch next noise row (hidden under this iteration's barriers)
        float4 nxA, nxB;
        if (L < 7) {
            const size_t nb = ((size_t)(b * NA) + (L + 1) * 4 + g) * 512 + 2 * r256;
            nxA = nzf4[nb]; nxB = nzf4[nb + 1];
        }

        const float wt = sw[i2][t];
        float z[8];
#pragma unroll
        for (int k = 0; k < 8; ++k) z[k] = fmaf(wt, d_[k], pi_[k]) + nzc[k];

        // butterfly sum over the 8 t's in this wave
#pragma unroll
        for (int k = 0; k < 8; ++k) {
            float s = z[k];
            s += __shfl_xor(s, 8);
            s += __shfl_xor(s, 16);
            s += __shfl_xor(s, 32);
            if (lil < 8) spart[wv][lil * 8 + k] = s;
        }
        __syncthreads();
        if (tid < 256) {
            const int gg = tid >> 6, c = tid & 63;
            szm[gg][c] = (spart[4 * gg][c] + spart[4 * gg + 1][c] +
                          spart[4 * gg + 2][c] + spart[4 * gg + 3][c]) * (1.0f / NA);
        }
        __syncthreads();

        float4* out4 = reinterpret_cast<float4*>(out) + (size_t)(b * NA + i2) * 1536;

        // z_mix region: 8 floats per thread
        const float4 zA = *reinterpret_cast<const float4*>(&szm[g][q * 8]);
        const float4 zB = *reinterpret_cast<const float4*>(&szm[g][q * 8 + 4]);
        const float zmv[8] = {zA.x, zA.y, zA.z, zA.w, zB.x, zB.y, zB.z, zB.w};
        float o[8];
#pragma unroll
        for (int k = 0; k < 8; ++k) o[k] = fmaf(pi_[k] - z[k], (1.0f / NA), zmv[k]);
        float4* oz = out4 + t * 48 + 32 + q * 2;
        oz[0] = make_float4(o[0], o[1], o[2], o[3]);
        oz[1] = make_float4(o[4], o[5], o[6], o[7]);

        // obs region: 4 float4 per thread from LDS
#pragma unroll
        for (int k2 = 0; k2 < 4; ++k2) {
            const int m  = r256 + 256 * k2;  // 0..1023
            const int tt = m >> 5;
            const int n  = m & 31;
            out4[tt * 48 + n] = so4[tt * 32 + n];
        }

        // rotate prefetched noise
        nzc[0] = nxA.x; nzc[1] = nxA.y; nzc[2] = nxA.z; nzc[3] = nxA.w;
        nzc[4] = nxB.x; nzc[5] = nxB.y; nzc[6] = nxB.z; nzc[7] = nxB.w;
    }
}

extern "C" void kernel_launch(void* const* d_in, const int* in_sizes, int n_in,
                              void* d_out, int out_size, void* d_ws, size_t ws_size,
                              hipStream_t stream) {
    const float* h        = (const float*)d_in[0];
    const float* policies = (const float*)d_in[1];
    const float* actions  = (const float*)d_in[2];
    const float* obs_proc = (const float*)d_in[3];
    const float* noise    = (const float*)d_in[4];
    const float* Wk       = (const float*)d_in[5];
    const float* bk       = (const float*)d_in[6];
    const float* Wq       = (const float*)d_in[7];
    const float* bq       = (const float*)d_in[8];

    float* out = (float*)d_out;
    float* obs_final = out;                                      // [8192,32,192]
    float* w_out = out + (size_t)NB * NA * NA * (NIN + NACT);    // [8192,32,1]

    fused_kernel<<<NB, 1024, 0, stream>>>(h, Wk, bk, Wq, bq,
                                          policies, actions, obs_proc, noise,
                                          obs_final, w_out);
}

// Round 8
// 73.578 us; speedup vs baseline: 1.2760x; 1.0028x over previous
//
#include <hip/hip_runtime.h>
#include <hip/hip_bf16.h>

// Problem constants
#define NA 32      // agents per graph
#define NACT 64    // actions
#define NIN 128    // in_dim
#define NOUT 128   // out_dim
#define NB 256     // graphs
// Inputs f32. Outputs f32: obs_final [8192,32,192] then w_out [8192,32,1].

// ---------------------------------------------------------------------------
// Fused kernel: one block per graph (grid=256, block=1024, 16 waves).
// Phase 1: stage h/obs/pi/act, project K/Q, scores+softmax -> sw + w_out.
// Phase 2 (BARRIER-FREE): wave wv handles dst rows i = 2*wv, 2*wv+1 alone.
//   Lane: qq = lane>>4 owns t = qq*8..qq*8+7; cg = lane&15 owns cols cg*4..+3.
//   S = sum_t z in regs; full 32-row sum via shfl_xor(16)+shfl_xor(32);
//   y[tt] = pi - z kept in regs; z_mix = (S + y)/32. No LDS combine, no syncs.
// ---------------------------------------------------------------------------
__global__ __launch_bounds__(1024) void fused_kernel(
    const float* __restrict__ h,
    const float* __restrict__ Wk, const float* __restrict__ bk,
    const float* __restrict__ Wq, const float* __restrict__ bq,
    const float* __restrict__ policies, const float* __restrict__ actions,
    const float* __restrict__ obs, const float* __restrict__ noise,
    float* __restrict__ out, float* __restrict__ w_out)
{
    __shared__ float sh[NA][NIN];         // 16 KB
    __shared__ float sK[NA][NOUT + 4];    // 16.5 KB
    __shared__ float sQ[NA][NOUT + 4];    // 16.5 KB
    __shared__ float sw[NA][NA];          // 4 KB   w[i][j]
    __shared__ float sobs[NA * NIN];      // 16 KB
    __shared__ float spi[NA][NACT];       // 8 KB
    __shared__ float sac[NA][NACT];       // 8 KB

    const int b   = blockIdx.x;
    const int tid = threadIdx.x;

    // ---- stage h + obs (1024 float4 each) and pi/act (512 float4 each)
    {
        const float4* hs = reinterpret_cast<const float4*>(h + (size_t)b * NA * NIN);
        reinterpret_cast<float4*>(&sh[0][0])[tid] = hs[tid];
        const float4* os = reinterpret_cast<const float4*>(obs + (size_t)b * NA * NIN);
        reinterpret_cast<float4*>(sobs)[tid] = os[tid];
        if (tid < 512) {
            reinterpret_cast<float4*>(&spi[0][0])[tid] =
                reinterpret_cast<const float4*>(policies + (size_t)b * 2048)[tid];
        } else {
            reinterpret_cast<float4*>(&sac[0][0])[tid - 512] =
                reinterpret_cast<const float4*>(actions + (size_t)b * 2048)[tid - 512];
        }
    }
    __syncthreads();

    // ---- phase 1a: projection (tx = out-dim 0..127, ty = node-group 0..7)
    {
        const int tx = tid & 127;
        const int ty = tid >> 7;
        float ak[4], aq[4];
        const float bkv = bk[tx];
        const float bqv = bq[tx];
#pragma unroll
        for (int s = 0; s < 4; ++s) { ak[s] = bkv; aq[s] = bqv; }
        for (int r = 0; r < NIN; r += 4) {
            const float wk0 = Wk[(r + 0) * NOUT + tx];
            const float wk1 = Wk[(r + 1) * NOUT + tx];
            const float wk2 = Wk[(r + 2) * NOUT + tx];
            const float wk3 = Wk[(r + 3) * NOUT + tx];
            const float wq0 = Wq[(r + 0) * NOUT + tx];
            const float wq1 = Wq[(r + 1) * NOUT + tx];
            const float wq2 = Wq[(r + 2) * NOUT + tx];
            const float wq3 = Wq[(r + 3) * NOUT + tx];
#pragma unroll
            for (int s = 0; s < 4; ++s) {
                const int n = ty * 4 + s;
                const float4 hv = *reinterpret_cast<const float4*>(&sh[n][r]);
                ak[s] = fmaf(hv.x, wk0, fmaf(hv.y, wk1, fmaf(hv.z, wk2, fmaf(hv.w, wk3, ak[s]))));
                aq[s] = fmaf(hv.x, wq0, fmaf(hv.y, wq1, fmaf(hv.z, wq2, fmaf(hv.w, wq3, aq[s]))));
            }
        }
#pragma unroll
        for (int s = 0; s < 4; ++s) {
            const int n = ty * 4 + s;
            sK[n][tx] = ak[s];
            sQ[n][tx] = aq[s];
        }
    }
    __syncthreads();

    // ---- phase 1b: scores + softmax (i = tid>>5 dst, j = tid&31 src)
    {
        const int i = tid >> 5;
        const int j = tid & 31;
        float sc = 0.f;
        for (int r = 0; r < NOUT; r += 4) {
            const float4 qv = *reinterpret_cast<const float4*>(&sQ[i][r]);
            const float4 kv = *reinterpret_cast<const float4*>(&sK[j][r]);
            sc = fmaf(qv.x, kv.x, fmaf(qv.y, kv.y, fmaf(qv.z, kv.z, fmaf(qv.w, kv.w, sc))));
        }
        sc *= 0.08838834764831845f;  // 1/sqrt(128)

        float m = sc;
#pragma unroll
        for (int off = 16; off >= 1; off >>= 1) m = fmaxf(m, __shfl_xor(m, off));
        const float e = __expf(sc - m);
        float ssum = e;
#pragma unroll
        for (int off = 16; off >= 1; off >>= 1) ssum += __shfl_xor(ssum, off);
        const float w = e / ssum;

        sw[i][j] = w;
        w_out[(size_t)b * (NA * NA) + tid] = w;
    }
    __syncthreads();   // last barrier — phase 2 is barrier-free

    // ---- phase 2: per-wave independent dst rows
    const int wv   = tid >> 6;    // wave 0..15
    const int lane = tid & 63;
    const int qq   = lane >> 4;   // t-quarter 0..3
    const int cg   = lane & 15;   // col group (4 floats)
    const int c0   = cg * 4;
    const float4* so4 = reinterpret_cast<const float4*>(sobs);

#pragma unroll
    for (int ii = 0; ii < 2; ++ii) {
        const int i = wv * 2 + ii;
        float4* out4 = reinterpret_cast<float4*>(out) + (size_t)(b * NA + i) * 1536;

        // pass 1: z = w*(act-pi)+pi+noise over this lane's 8 t's
        float S0 = 0.f, S1 = 0.f, S2 = 0.f, S3 = 0.f;
        float y[8][4];
        const float* nzb = noise + (((size_t)(b * NA + i)) * 32 + qq * 8) * 64 + c0;
#pragma unroll
        for (int tt = 0; tt < 8; ++tt) {
            const int t = qq * 8 + tt;
            const float wt = sw[i][t];
            const float4 p4 = *reinterpret_cast<const float4*>(&spi[t][c0]);
            const float4 a4 = *reinterpret_cast<const float4*>(&sac[t][c0]);
            const float4 n4 = *reinterpret_cast<const float4*>(nzb + tt * 64);
            float z;
            z = fmaf(wt, a4.x - p4.x, p4.x) + n4.x; S0 += z; y[tt][0] = p4.x - z;
            z = fmaf(wt, a4.y - p4.y, p4.y) + n4.y; S1 += z; y[tt][1] = p4.y - z;
            z = fmaf(wt, a4.z - p4.z, p4.z) + n4.z; S2 += z; y[tt][2] = p4.z - z;
            z = fmaf(wt, a4.w - p4.w, p4.w) + n4.w; S3 += z; y[tt][3] = p4.w - z;
        }
        // complete the 32-row sum across quarters (lanes xor 16, 32)
        S0 += __shfl_xor(S0, 16); S0 += __shfl_xor(S0, 32);
        S1 += __shfl_xor(S1, 16); S1 += __shfl_xor(S1, 32);
        S2 += __shfl_xor(S2, 16); S2 += __shfl_xor(S2, 32);
        S3 += __shfl_xor(S3, 16); S3 += __shfl_xor(S3, 32);

        // pass 2: z_mix = (S + y) / 32, store
#pragma unroll
        for (int tt = 0; tt < 8; ++tt) {
            const int t = qq * 8 + tt;
            float4 o;
            o.x = (S0 + y[tt][0]) * (1.0f / NA);
            o.y = (S1 + y[tt][1]) * (1.0f / NA);
            o.z = (S2 + y[tt][2]) * (1.0f / NA);
            o.w = (S3 + y[tt][3]) * (1.0f / NA);
            out4[t * 48 + 32 + cg] = o;
        }

        // obs region: 32 t-rows x 32 float4, from LDS
#pragma unroll
        for (int k = 0; k < 16; ++k) {
            const int idx = lane + 64 * k;     // 0..1023
            const int t2  = idx >> 5;
            const int nn  = idx & 31;
            out4[t2 * 48 + nn] = so4[t2 * 32 + nn];
        }
    }
}

extern "C" void kernel_launch(void* const* d_in, const int* in_sizes, int n_in,
                              void* d_out, int out_size, void* d_ws, size_t ws_size,
                              hipStream_t stream) {
    const float* h        = (const float*)d_in[0];
    const float* policies = (const float*)d_in[1];
    const float* actions  = (const float*)d_in[2];
    const float* obs_proc = (const float*)d_in[3];
    const float* noise    = (const float*)d_in[4];
    const float* Wk       = (const float*)d_in[5];
    const float* bk       = (const float*)d_in[6];
    const float* Wq       = (const float*)d_in[7];
    const float* bq       = (const float*)d_in[8];

    float* out = (float*)d_out;
    float* obs_final = out;                                      // [8192,32,192]
    float* w_out = out + (size_t)NB * NA * NA * (NIN + NACT);    // [8192,32,1]

    fused_kernel<<<NB, 1024, 0, stream>>>(h, Wk, bk, Wq, bq,
                                          policies, actions, obs_proc, noise,
                                          obs_final, w_out);
}